// Round 4
// baseline (817.469 us; speedup 1.0000x reference)
//
#include <hip/hip_runtime.h>
#include <math.h>

typedef __bf16 bf16;
typedef __bf16 bf16x8 __attribute__((ext_vector_type(8)));
typedef float  f32x4  __attribute__((ext_vector_type(4)));

#define MFMA16(a,b,c) __builtin_amdgcn_mfma_f32_16x16x32_bf16((a),(b),(c),0,0,0)

#define B_SZ 4096
#define T_SZ 200
#define D_SZ 128
#define U_SZ 128
#define ACHUNK 4
#define AROWS 16
#define NCH (T_SZ / ACHUNK)   // 50

__device__ __forceinline__ float frcp_(float x) { return __builtin_amdgcn_rcpf(x); }
__device__ __forceinline__ float fsig(float x)  { return frcp_(1.0f + __expf(-x)); }
__device__ __forceinline__ float ftanh_(float x){ return 1.0f - 2.0f * frcp_(1.0f + __expf(2.0f * x)); }
__device__ __forceinline__ float dicef(float x, float alpha) {
    float p = fsig(x);
    return alpha * (1.0f - p) * x + p * x;
}
// Barrier waiting ONLY lgkmcnt (LDS visibility); global loads stay in flight.
__device__ __forceinline__ void bar_lgkm() {
    asm volatile("s_waitcnt lgkmcnt(0)\n\ts_barrier" ::: "memory");
}

// ---------------------------------------------------------------------------
// Prep (unchanged): bias1 = q@(W1a+W1c); W1' -> bf16 [n][256]; W2^T -> bf16.
// ---------------------------------------------------------------------------
__global__ __launch_bounds__(256) void prep_kernel(
    const float* __restrict__ Q,    // [B,128]
    const float* __restrict__ W1,   // [512,64]
    const float* __restrict__ W2,   // [64,16]
    float* __restrict__ BIAS,       // [B,64]
    bf16*  __restrict__ W1P,        // [64][256]
    bf16*  __restrict__ W2T)        // [16][64]
{
    const int tid = threadIdx.x;
    if (blockIdx.x == 256) {
        #pragma unroll 4
        for (int it = 0; it < 64; ++it) {
            int idx = it * 256 + tid;
            int k = idx >> 6;
            int n = idx & 63;
            float v;
            if (k < 128) v = W1[(128 + k) * 64 + n] - W1[(256 + k) * 64 + n];
            else         v = W1[(384 + (k - 128)) * 64 + n];
            W1P[n * 256 + k] = (bf16)v;
        }
        #pragma unroll
        for (int it = 0; it < 4; ++it) {
            int idx = it * 256 + tid; int k = idx >> 4; int n = idx & 15;
            W2T[n * 64 + k] = (bf16)W2[k * 16 + n];
        }
        return;
    }
    const int b0   = blockIdx.x * 16;
    const int lane = tid & 63;
    const int w    = tid >> 6;
    const int quad = lane >> 4;
    const int l15  = lane & 15;

    bf16x8 a[4];
    #pragma unroll
    for (int kk = 0; kk < 4; ++kk) {
        const float* p = Q + (long)(b0 + l15) * D_SZ + kk * 32 + quad * 8;
        float4 x0 = ((const float4*)p)[0];
        float4 x1 = ((const float4*)p)[1];
        float xv[8] = {x0.x, x0.y, x0.z, x0.w, x1.x, x1.y, x1.z, x1.w};
        #pragma unroll
        for (int j = 0; j < 8; ++j) a[kk][j] = (bf16)xv[j];
    }
    const int n = w * 16 + l15;
    f32x4 acc = {};
    #pragma unroll
    for (int kk = 0; kk < 4; ++kk) {
        bf16x8 bf;
        #pragma unroll
        for (int j = 0; j < 8; ++j) {
            int k = kk * 32 + quad * 8 + j;
            bf[j] = (bf16)(W1[k * 64 + n] + W1[(256 + k) * 64 + n]);
        }
        acc = MFMA16(a[kk], bf, acc);
    }
    #pragma unroll
    for (int i = 0; i < 4; ++i)
        BIAS[(long)(b0 + quad * 4 + i) * 64 + n] = acc[i];
}

// ---------------------------------------------------------------------------
// Fused kernel. 512 threads = 8 waves (2/SIMD). Waves 0-3: AUGRU scan, each
// wave owns TWO 16-col output tiles (halves the 8x broadcast duplication of
// Hb/RHb/Xs A-fragment reads: 96 -> 48 ds_read_b128 per step — the LDS pipe
// was the measured bottleneck). x-part MFMAs merged into the two phases (no
// persistent xpart accumulators -> fits ~250 VGPR with Wf=192).
// Waves 4-7: producers (X load/stage 2 chunks ahead, attention h1/h23 -> As),
// schedule identical to round 3 except qf is read as float4 (the scalar qf
// reads were 4x over the bank-conflict floor). Barrier ledger: 1 + 8*NCH.
// ---------------------------------------------------------------------------
__global__ __launch_bounds__(512, 2) void fused_kernel(
    const float* __restrict__ X,    // [B,T,D]
    const float* __restrict__ Q,    // [B,128]
    const int*   __restrict__ LEN,  // [B,1]
    const float* __restrict__ A1,   // [64]
    const float* __restrict__ A2g,  // [16]
    const float* __restrict__ W3g,  // [16,1]
    const float* __restrict__ BIAS, // [B,64]
    const bf16*  __restrict__ W1P,  // [64][256]
    const bf16*  __restrict__ W2T,  // [16][64]
    const float* __restrict__ WU,   // [256,128]
    const float* __restrict__ WR,
    const float* __restrict__ WC,
    float* __restrict__ OUT)        // [B,128]
{
    __shared__ bf16  Xs[2][ACHUNK][16][136];   // 34.8 KB
    __shared__ bf16  Hb[16][136];
    __shared__ bf16  RHb[16][136];
    __shared__ bf16  H1p[4][16][72];           // per-producer dice(h1) scratch
    __shared__ bf16  W1s[64][264];             // 33.8 KB
    __shared__ float qf[16][132];              // fp32 q (rows 16B-aligned)
    __shared__ float bias_s[16][68];
    __shared__ float As[2][64];                // double-buffered attn scores
    __shared__ int   lens16[16];

    const int tid  = threadIdx.x;
    const int lane = tid & 63;
    const int w    = tid >> 6;      // 0..7
    const int quad = lane >> 4;
    const int l15  = lane & 15;
    const int b0   = blockIdx.x * AROWS;

    // ---- cooperative staging (all 8 waves) ----
    for (int idx = tid; idx < 64 * 32; idx += 512) {
        int nn = idx >> 5, k8 = idx & 31;
        *(bf16x8*)&W1s[nn][k8 * 8] = *(const bf16x8*)(W1P + nn * 256 + k8 * 8);
    }
    for (int i = tid; i < 16 * 128; i += 512) {
        int r = i >> 7, k = i & 127;
        qf[r][k] = Q[(long)(b0 + r) * D_SZ + k];
    }
    for (int i = tid; i < 16 * 64; i += 512) {
        int r = i >> 6, cc = i & 63;
        bias_s[r][cc] = BIAS[(long)(b0 + r) * 64 + cc];
    }
    if (tid < 16) lens16[tid] = LEN[b0 + tid];
    for (int i = tid; i < 16 * 136; i += 512) {
        ((bf16*)Hb)[i] = (bf16)0.f; ((bf16*)RHb)[i] = (bf16)0.f;
    }
    __syncthreads();

    if (w < 4) {
        // ================= SCAN branch (waves 0-3, 2 tiles each) =============
        const int n0 = w * 32 + l15;           // first owned column
        bf16x8 Wf[3][2][4][2];                 // [gate][part][kk][tile] 192 VGPR
        {
            const float* Wg[3] = {WU, WR, WC};
            #pragma unroll
            for (int g = 0; g < 3; ++g)
                #pragma unroll
                for (int p = 0; p < 2; ++p)
                    #pragma unroll
                    for (int kk = 0; kk < 4; ++kk)
                        #pragma unroll
                        for (int t = 0; t < 2; ++t) {
                            #pragma unroll
                            for (int i = 0; i < 8; ++i) {
                                int k = p * 128 + kk * 32 + quad * 8 + i;
                                Wf[g][p][kk][t][i] = (bf16)Wg[g][k * 128 + n0 + t * 16];
                            }
                        }
        }
        float h0[4] = {0.f, 0.f, 0.f, 0.f};
        float h1[4] = {0.f, 0.f, 0.f, 0.f};

        bar_lgkm();                  // bar#0: producer prologue done (Xs[0], As[0])

        for (int c = 0; c < NCH; ++c) {
            const int buf = c & 1;
            #pragma unroll
            for (int s = 0; s < ACHUNK; ++s) {
                // ---- phase 1: r,u gates (x-part + h-part) ----
                bf16x8 ah[4], ax[4];
                #pragma unroll
                for (int kk = 0; kk < 4; ++kk) {
                    ah[kk] = *(const bf16x8*)&Hb[l15][kk * 32 + quad * 8];
                    ax[kk] = *(const bf16x8*)&Xs[buf][s][l15][kk * 32 + quad * 8];
                }
                f32x4 pr0 = {}, pr1 = {}, pu0 = {}, pu1 = {};
                __builtin_amdgcn_s_setprio(1);
                #pragma unroll
                for (int kk = 0; kk < 4; ++kk) {
                    pr0 = MFMA16(ax[kk], Wf[1][0][kk][0], pr0);
                    pr1 = MFMA16(ax[kk], Wf[1][0][kk][1], pr1);
                    pu0 = MFMA16(ax[kk], Wf[0][0][kk][0], pu0);
                    pu1 = MFMA16(ax[kk], Wf[0][0][kk][1], pu1);
                }
                #pragma unroll
                for (int kk = 0; kk < 4; ++kk) {
                    pr0 = MFMA16(ah[kk], Wf[1][1][kk][0], pr0);
                    pr1 = MFMA16(ah[kk], Wf[1][1][kk][1], pr1);
                    pu0 = MFMA16(ah[kk], Wf[0][1][kk][0], pu0);
                    pu1 = MFMA16(ah[kk], Wf[0][1][kk][1], pu1);
                }
                __builtin_amdgcn_s_setprio(0);
                float uu0[4], uu1[4];
                #pragma unroll
                for (int i = 0; i < 4; ++i) {
                    RHb[quad * 4 + i][n0]      = (bf16)(fsig(pr0[i]) * h0[i]);
                    RHb[quad * 4 + i][n0 + 16] = (bf16)(fsig(pr1[i]) * h1[i]);
                    uu0[i] = fsig(pu0[i]);
                    uu1[i] = fsig(pu1[i]);
                }
                bar_lgkm();
                // ---- phase 2: c gate (x-part with kept ax + h-part on RHb) --
                bf16x8 ar[4];
                #pragma unroll
                for (int kk = 0; kk < 4; ++kk)
                    ar[kk] = *(const bf16x8*)&RHb[l15][kk * 32 + quad * 8];
                f32x4 pc0 = {}, pc1 = {};
                __builtin_amdgcn_s_setprio(1);
                #pragma unroll
                for (int kk = 0; kk < 4; ++kk) {
                    pc0 = MFMA16(ax[kk], Wf[2][0][kk][0], pc0);
                    pc1 = MFMA16(ax[kk], Wf[2][0][kk][1], pc1);
                }
                #pragma unroll
                for (int kk = 0; kk < 4; ++kk) {
                    pc0 = MFMA16(ar[kk], Wf[2][1][kk][0], pc0);
                    pc1 = MFMA16(ar[kk], Wf[2][1][kk][1], pc1);
                }
                __builtin_amdgcn_s_setprio(0);
                #pragma unroll
                for (int i = 0; i < 4; ++i) {
                    float a   = As[buf][s * 16 + quad * 4 + i];
                    float cg0 = ftanh_(pc0[i]);
                    float cg1 = ftanh_(pc1[i]);
                    float ut0 = uu0[i] * a;
                    float ut1 = uu1[i] * a;
                    h0[i] = (1.f - ut0) * h0[i] + ut0 * cg0;
                    h1[i] = (1.f - ut1) * h1[i] + ut1 * cg1;
                    Hb[quad * 4 + i][n0]      = (bf16)h0[i];
                    Hb[quad * 4 + i][n0 + 16] = (bf16)h1[i];
                }
                bar_lgkm();
            }
        }
        #pragma unroll
        for (int i = 0; i < 4; ++i) {
            OUT[(long)(b0 + quad * 4 + i) * U_SZ + n0]      = h0[i];
            OUT[(long)(b0 + quad * 4 + i) * U_SZ + n0 + 16] = h1[i];
        }
    } else {
        // ================= PRODUCER branch (waves 4-7) =================
        const int pw = w - 4;                  // owned slice (0..3)
        float al1r[4];
        #pragma unroll
        for (int nt = 0; nt < 4; ++nt) al1r[nt] = A1[nt * 16 + l15];
        const float al2v = A2g[l15];
        const float w3v  = W3g[l15];
        bf16x8 b2f[2];
        #pragma unroll
        for (int kk = 0; kk < 2; ++kk)
            b2f[kk] = *(const bf16x8*)(W2T + l15 * 64 + kk * 32 + quad * 8);

        float4 pf[8];
        bf16x8 axp[4], aqp[4];

        auto p_issue = [&](int cn) {          // load slice pw of chunk cn
            const float* xp = X + ((long)(b0 + l15) * T_SZ + cn * ACHUNK + pw) * D_SZ;
            #pragma unroll
            for (int kk = 0; kk < 4; ++kk) {
                const float* p = xp + kk * 32 + quad * 8;
                pf[kk * 2]     = ((const float4*)p)[0];
                pf[kk * 2 + 1] = ((const float4*)p)[1];
            }
        };
        auto p_convert = [&]() {              // pf -> axp (bf16 x), aqp (bf16 x*q)
            #pragma unroll
            for (int kk = 0; kk < 4; ++kk) {
                float4 xa = pf[kk * 2], xb = pf[kk * 2 + 1];
                float4 qa = *(const float4*)&qf[l15][kk * 32 + quad * 8];
                float4 qb = *(const float4*)&qf[l15][kk * 32 + quad * 8 + 4];
                float xv[8] = {xa.x, xa.y, xa.z, xa.w, xb.x, xb.y, xb.z, xb.w};
                float qv[8] = {qa.x, qa.y, qa.z, qa.w, qb.x, qb.y, qb.z, qb.w};
                #pragma unroll
                for (int j = 0; j < 8; ++j) {
                    axp[kk][j] = (bf16)xv[j];
                    aqp[kk][j] = (bf16)(xv[j] * qv[j]);
                }
            }
        };
        auto p_writeXs = [&](int xb) {        // b128 stores, conflict-free
            #pragma unroll
            for (int kk = 0; kk < 4; ++kk)
                *(bf16x8*)&Xs[xb][pw][l15][kk * 32 + quad * 8] = axp[kk];
        };
        auto p_h1 = [&](int nt) {             // one 16x16 tile of h1, K=256
            f32x4 acc = {};
            #pragma unroll
            for (int kk = 0; kk < 4; ++kk) {
                bf16x8 bw = *(const bf16x8*)&W1s[nt * 16 + l15][kk * 32 + quad * 8];
                acc = MFMA16(axp[kk], bw, acc);
            }
            #pragma unroll
            for (int kk = 0; kk < 4; ++kk) {
                bf16x8 bw = *(const bf16x8*)&W1s[nt * 16 + l15][128 + kk * 32 + quad * 8];
                acc = MFMA16(aqp[kk], bw, acc);
            }
            #pragma unroll
            for (int i = 0; i < 4; ++i) {
                int row = quad * 4 + i;
                float v = acc[i] + bias_s[row][nt * 16 + l15];
                H1p[pw][row][nt * 16 + l15] = (bf16)dicef(v, al1r[nt]);
            }
        };
        auto p_h23 = [&](int cn, int ab) {    // h2/h3/sigmoid -> As[ab]
            f32x4 acc2 = {};
            #pragma unroll
            for (int kk = 0; kk < 2; ++kk) {
                bf16x8 a2 = *(const bf16x8*)&H1p[pw][l15][kk * 32 + quad * 8];
                acc2 = MFMA16(a2, b2f[kk], acc2);
            }
            float sv[4];
            #pragma unroll
            for (int i = 0; i < 4; ++i) sv[i] = dicef(acc2[i], al2v) * w3v;
            #pragma unroll
            for (int i = 0; i < 4; ++i) {
                sv[i] += __shfl_xor(sv[i], 1, 64);
                sv[i] += __shfl_xor(sv[i], 2, 64);
                sv[i] += __shfl_xor(sv[i], 4, 64);
                sv[i] += __shfl_xor(sv[i], 8, 64);
            }
            if (l15 == 0) {
                int t = cn * ACHUNK + pw;
                #pragma unroll
                for (int i = 0; i < 4; ++i) {
                    int row = quad * 4 + i;
                    As[ab][pw * 16 + row] = (t < lens16[row]) ? fsig(sv[i]) : 0.0f;
                }
            }
        };

        // ---- prologue: fully prepare chunk 0; prime loads for chunk 1 ----
        p_issue(0);
        p_convert();
        p_writeXs(0);
        p_h1(0); p_h1(1); p_h1(2); p_h1(3);
        p_h23(0, 0);
        if (NCH > 1) p_issue(1);
        bar_lgkm();                  // bar#0

        // ---- main loop: during chunk c, prepare chunk cn=c+1; load c+2 ----
        for (int c = 0; c < NCH; ++c) {
            const int cn = c + 1;
            const int xb = cn & 1;
            const bool act = cn < NCH;
            // slot A0
            if (act) { p_convert(); p_writeXs(xb); }
            bar_lgkm();
            // slot B0
            if (c + 2 < NCH) p_issue(c + 2);
            bar_lgkm();
            // slot A1
            if (act) p_h1(0);
            bar_lgkm();
            // slot B1
            if (act) p_h1(1);
            bar_lgkm();
            // slot A2
            if (act) p_h1(2);
            bar_lgkm();
            // slot B2
            if (act) p_h1(3);
            bar_lgkm();
            // slot A3
            if (act) p_h23(cn, xb);
            bar_lgkm();
            // slot B3 (slack)
            bar_lgkm();
        }
    }
}

extern "C" void kernel_launch(void* const* d_in, const int* in_sizes, int n_in,
                              void* d_out, int out_size, void* d_ws, size_t ws_size,
                              hipStream_t stream) {
    const float* X   = (const float*)d_in[0];
    const float* Q   = (const float*)d_in[1];
    const int*   LEN = (const int*)d_in[2];
    const float* W1  = (const float*)d_in[3];
    const float* A1  = (const float*)d_in[4];
    const float* W2  = (const float*)d_in[5];
    const float* A2  = (const float*)d_in[6];
    const float* W3  = (const float*)d_in[7];
    const float* WU  = (const float*)d_in[8];
    const float* WR  = (const float*)d_in[9];
    const float* WC  = (const float*)d_in[10];
    float* OUT = (float*)d_out;

    float* BIAS = (float*)d_ws;                       // B*64 fp32
    bf16*  W1P  = (bf16*)(BIAS + (size_t)B_SZ * 64);  // 64*256 bf16
    bf16*  W2T  = W1P + 64 * 256;                     // 16*64 bf16

    prep_kernel<<<257, 256, 0, stream>>>(Q, W1, W2, BIAS, W1P, W2T);
    fused_kernel<<<B_SZ / AROWS, 512, 0, stream>>>(X, Q, LEN, A1, A2, W3,
                                                   BIAS, W1P, W2T, WU, WR, WC, OUT);
}